// Round 6
// baseline (482.824 us; speedup 1.0000x reference)
//
#include <hip/hip_runtime.h>
#include <stdint.h>

typedef float f32x4 __attribute__((ext_vector_type(4)));
typedef float f32x2 __attribute__((ext_vector_type(2)));
typedef short bf16x8 __attribute__((ext_vector_type(8)));
typedef uint32_t u32x4 __attribute__((ext_vector_type(4)));

__device__ __forceinline__ uint32_t bf16_rne(float f) {
  uint32_t x = __float_as_uint(f);
  return (x + 0x7FFFu + ((x >> 16) & 1u)) >> 16;
}

// LDS-only barrier: waits this wave's DS ops, does NOT drain vmcnt.
// Memory clobber pins global-load issue placement per phase.
__device__ __forceinline__ void ldsbar() {
  asm volatile("s_waitcnt lgkmcnt(0)\n\ts_barrier" ::: "memory");
}

// ---------------- kernel 0: cast x (f32) -> bf16 ----------------
__global__ void cast_x_kernel(const float* __restrict__ x,
                              uint32_t* __restrict__ xb, int n2) {
  int i = blockIdx.x * 256 + threadIdx.x;
  if (i >= n2) return;
  f32x2 v = *(const f32x2*)(x + 2 * i);
  xb[i] = bf16_rne(v[0]) | (bf16_rne(v[1]) << 16);
}

// ---------------- per-class GEMM, weights-once, deep pipeline ----------------
// Block: M=256 (full batch) x N=64 of one class, BK=64, 8 waves (8M x 1N),
// wave tile 32x64, acc[2][4]=32 VGPR. 1 block/CU (VGPR cap 256 -> no spill).
// A: bf16 from global (L2/L3-resident), 2-deep register prefetch.
// B: W f32 column loads, 4-deep register rotation -> bf16 pack -> swizzled
//    ds_write_b128, double-buffered LDS (16 KB total).
// vmcnt stream strictly monotone: comp(t) waits A(t) (the oldest), leaving
// B(t+2..t+4)/A(t+1) in flight; barriers lgkm-only -> HBM W-stream never
// drains. Same class -> same XCD in both layers (h1 L2 locality).
// MODE 0: bias+relu -> bf16 h1 store.  MODE 1: bias+relu -> W3 dot ->
// shfl-reduce -> f32 partials (layer 3 fused).
template <int K, int MODE>
__global__ __launch_bounds__(512, 2) void gemm_fused(
    const uint16_t* __restrict__ Abase, long long aClassStride,
    const float* __restrict__ Wbase, const float* __restrict__ biasBase,
    uint16_t* __restrict__ Hout, const float* __restrict__ W3base,
    float* __restrict__ part) {
  constexpr int NT = K / 64;
  __shared__ uint8_t smem[16384];  // 2 x (B 8K)

  const int tid = threadIdx.x;
  const int bid = blockIdx.x;
  // bijective XCD swizzle: xcd(bid&7) gets classes [xcd*64, xcd*64+63]
  const int logical = ((bid & 7) << 9) | (bid >> 3);
  const int c = logical >> 3;
  const int nt = logical & 7;
  const int n0 = nt * 64;

  const uint16_t* Ab = Abase + (size_t)c * (size_t)aClassStride;
  const float* Wc = Wbase + (size_t)c * (K * 512) + n0;

  const int l = tid & 63, w = tid >> 6;
  const int lr = l & 15, lg = l >> 4;

  // lane's A base: row (w*32 + lr), k-octet lg
  const uint16_t* Ap = Ab + (size_t)(w * 32 + lr) * K + lg * 8;

  // ---- early small loads (oldest in vmcnt stream; never drain W later) ----
  float bv[4], w30[4], w31[4];
#pragma unroll
  for (int nf = 0; nf < 4; nf++)
    bv[nf] = biasBase[c * 512 + n0 + nf * 16 + lr];
  if constexpr (MODE == 1) {
#pragma unroll
    for (int nf = 0; nf < 4; nf++) {
      f32x2 t = *(const f32x2*)(W3base +
                                ((size_t)c * 512 + n0 + nf * 16 + lr) * 2);
      w30[nf] = t[0];
      w31[nf] = t[1];
    }
  }

  f32x4 acc[2][4];
#pragma unroll
  for (int i = 0; i < 2; i++)
#pragma unroll
    for (int j = 0; j < 4; j++) acc[i][j] = {0.f, 0.f, 0.f, 0.f};

  auto loadB = [&](int ts, float* g) {
    const float* Ws = Wc + (size_t)(ts * 64 + w * 8) * 512 + l;
#pragma unroll
    for (int r = 0; r < 8; r++) g[r] = Ws[(size_t)r * 512];
  };
  auto loadA = [&](int ts, bf16x8* as) {
#pragma unroll
    for (int kk = 0; kk < 2; ++kk)
#pragma unroll
      for (int mf = 0; mf < 2; mf++)
        as[kk * 2 + mf] =
            *(const bf16x8*)(Ap + ts * 64 + kk * 32 + (size_t)mf * 16 * K);
  };
  auto writeB = [&](const float* g, int buf) {
    u32x4 p;
#pragma unroll
    for (int j = 0; j < 4; j++)
      p[j] = bf16_rne(g[2 * j]) | (bf16_rne(g[2 * j + 1]) << 16);
    *(u32x4*)(smem + buf * 8192 + l * 128 + ((w ^ (l & 7)) << 4)) = p;
  };
  auto comp = [&](int buf, const bf16x8* as) {
    const uint8_t* s = smem + buf * 8192;
#pragma unroll
    for (int kk = 0; kk < 2; ++kk) {
      const int kx = ((lg * 16) ^ ((lr & 7) << 4)) ^ (kk << 6);
      bf16x8 b[4];
#pragma unroll
      for (int nf = 0; nf < 4; nf++)
        b[nf] = *(const bf16x8*)(s + (nf * 16 + lr) * 128 + kx);
#pragma unroll
      for (int mf = 0; mf < 2; mf++)
#pragma unroll
        for (int nf = 0; nf < 4; nf++)
          acc[mf][nf] = __builtin_amdgcn_mfma_f32_16x16x32_bf16(
              as[kk * 2 + mf], b[nf], acc[mf][nf], 0, 0, 0);
    }
  };

  float g[4][8];
  bf16x8 a[2][4];
  // prologue issue order chosen to match steady-state wait pattern
  loadB(0, g[0]);
  loadB(1, g[1]);
  loadA(0, a[0]);
  loadB(2, g[2]);
  loadA(1, a[1]);
  loadB(3, g[3]);
  writeB(g[0], 0);  // waits only B(0); everything younger stays in flight
  ldsbar();

#pragma unroll
  for (int t = 0; t < NT; ++t) {
    comp(t & 1, a[t & 1]);                                // waits A(t)
    if (t + 1 < NT) writeB(g[(t + 1) & 3], (t + 1) & 1);  // wait already met
    if (t + 2 < NT) loadA(t + 2, a[t & 1]);               // 2 phases ahead
    if (t + 4 < NT) loadB(t + 4, g[t & 3]);               // 4 phases ahead
    if (t + 1 < NT) ldsbar();                             // publish buf
  }

  if constexpr (MODE == 0) {
    uint16_t* Oc = Hout + (size_t)c * 131072 + n0;
#pragma unroll
    for (int mf = 0; mf < 2; mf++)
#pragma unroll
      for (int nf = 0; nf < 4; nf++)
#pragma unroll
        for (int r = 0; r < 4; r++) {
          int m = w * 32 + mf * 16 + lg * 4 + r;
          float v = fmaxf(acc[mf][nf][r] + bv[nf], 0.f);
          Oc[(size_t)m * 512 + nf * 16 + lr] = (uint16_t)bf16_rne(v);
        }
  } else {
#pragma unroll
    for (int mf = 0; mf < 2; mf++)
#pragma unroll
      for (int r = 0; r < 4; r++) {
        float s0 = 0.f, s1 = 0.f;
#pragma unroll
        for (int nf = 0; nf < 4; nf++) {
          float v = fmaxf(acc[mf][nf][r] + bv[nf], 0.f);
          s0 += v * w30[nf];
          s1 += v * w31[nf];
        }
#pragma unroll
        for (int d = 1; d < 16; d <<= 1) {
          s0 += __shfl_xor(s0, d);
          s1 += __shfl_xor(s1, d);
        }
        if (lr == 0) {
          int m = w * 32 + mf * 16 + lg * 4 + r;
          *(f32x2*)(part + (((size_t)c * 256 + m) * 8 + nt) * 2) =
              f32x2{s0, s1};
        }
      }
  }
}

// ---------------- reduce partials -> out [B][C][2] ----------------
__global__ __launch_bounds__(512) void reduce_out(
    const float* __restrict__ part, const float* __restrict__ b3,
    float* __restrict__ out) {
  const int b = blockIdx.x, c = threadIdx.x;
  const f32x4* p = (const f32x4*)(part + ((size_t)c * 256 + b) * 16);
  f32x4 v0 = p[0], v1 = p[1], v2 = p[2], v3 = p[3];
  float s0 = b3[c * 2] + v0[0] + v0[2] + v1[0] + v1[2] + v2[0] + v2[2] +
             v3[0] + v3[2];
  float s1 = b3[c * 2 + 1] + v0[1] + v0[3] + v1[1] + v1[3] + v2[1] + v2[3] +
             v3[1] + v3[3];
  *(f32x2*)(out + ((size_t)b * 512 + c) * 2) = f32x2{s0, s1};
}

extern "C" void kernel_launch(void* const* d_in, const int* in_sizes, int n_in,
                              void* d_out, int out_size, void* d_ws,
                              size_t ws_size, hipStream_t stream) {
  const float* x = (const float*)d_in[0];
  const float* W1 = (const float*)d_in[1];
  const float* b1 = (const float*)d_in[2];
  const float* W2 = (const float*)d_in[3];
  const float* b2 = (const float*)d_in[4];
  const float* W3 = (const float*)d_in[5];
  const float* b3 = (const float*)d_in[6];
  float* out = (float*)d_out;

  uint8_t* ws = (uint8_t*)d_ws;
  const size_t xb_off = 0;
  const size_t h1_off = 393216;                // 256*768*2
  const size_t part_off = h1_off + 134217728;  // + 512*256*512*2
  const size_t need = part_off + 8388608;      // + 512*256*8*2*4
  if (ws_size < need) return;

  uint32_t* xb = (uint32_t*)(ws + xb_off);
  uint16_t* h1 = (uint16_t*)(ws + h1_off);
  float* part = (float*)(ws + part_off);

  cast_x_kernel<<<dim3(384), dim3(256), 0, stream>>>(x, xb, 98304);
  gemm_fused<768, 0><<<dim3(4096), dim3(512), 0, stream>>>(
      (const uint16_t*)xb, 0LL, W1, b1, h1, nullptr, nullptr);
  gemm_fused<512, 1><<<dim3(4096), dim3(512), 0, stream>>>(
      h1, 131072LL, W2, b2, nullptr, W3, part);
  reduce_out<<<dim3(256), dim3(512), 0, stream>>>(part, b3, out);
}